// Round 7
// baseline (2738.563 us; speedup 1.0000x reference)
//
#include <hip/hip_runtime.h>

typedef unsigned int u32;
typedef __fp16 f16;
typedef __fp16 h2 __attribute__((ext_vector_type(2)));
typedef __fp16 h4 __attribute__((ext_vector_type(4)));
typedef __fp16 h8 __attribute__((ext_vector_type(8)));
typedef float f32x2v __attribute__((ext_vector_type(2)));
typedef float f32x4v __attribute__((ext_vector_type(4)));
typedef float f32x16v __attribute__((ext_vector_type(16)));
typedef u32 u32x2v __attribute__((ext_vector_type(2)));
typedef u32 u32x4v __attribute__((ext_vector_type(4)));

static constexpr int BB = 64;     // batch
static constexpr int TT = 1024;   // seq len
static constexpr int HH = 256;    // hidden
static constexpr int GG = 768;    // 3*H
static constexpr size_t GI_BYTES = (size_t)BB * TT * GG * 2;  // f16 gi buffer

__device__ __forceinline__ u32 pk2(float a, float b) {
  h2 r = __builtin_amdgcn_cvt_pkrtz(a, b);
  return __builtin_bit_cast(u32, r);
}
__device__ __forceinline__ float dpp_shr8(float x) {  // row_shr:8 -> dst[i]=src[i-8]
  return __builtin_bit_cast(float,
      __builtin_amdgcn_mov_dpp(__builtin_bit_cast(int, x), 0x118, 0xF, 0xF, true));
}
__device__ __forceinline__ float sigf(float x) { return 1.f / (1.f + __expf(-x)); }
__device__ __forceinline__ float tanhf2(float x) {
  float e = __expf(2.f * x);
  return 1.f - 2.f / (e + 1.f);
}

// ---------------------------------------------------------------------------
// Phase 0: prepack W_hh (768x256 f32) into MFMA A-fragment order (f16).
// recur wave w, lane l, frag i = ti6*8+ks (ti6 = G*2+tj), dword e2:
//   A tile m = G*16 + 2w + tj ; row = 16m + (l&15) ; k = 32ks + 8(l>>4) + 2e2
// Wa dword index = (w*64+l)*192 + i*4 + e2  → recur init loads b128, coalesced.
// ---------------------------------------------------------------------------
__global__ void prepack_wa(const float* __restrict__ Whh, u32* __restrict__ Wa) {
  int id = blockIdx.x * 256 + threadIdx.x;  // [0, 98304)
  int lane_g = id / 192;
  int rrem = id - lane_g * 192;
  int i = rrem >> 2, e2 = rrem & 3;
  int ti6 = i >> 3, ks = i & 7;
  int G = ti6 >> 1, tj = ti6 & 1;
  int w = lane_g >> 6, l = lane_g & 63;
  int m = G * 16 + 2 * w + tj;
  int row = 16 * m + (l & 15);
  int k = 32 * ks + 8 * (l >> 4) + 2 * e2;
  const float* p = Whh + (size_t)row * HH + k;
  Wa[id] = pk2(p[0], p[1]);
}

// ---------------------------------------------------------------------------
// Phase 1: gi = x @ W_ih^T + b_ih (+ b_hh folded for r,z gates), stored f16.
// ---------------------------------------------------------------------------
__device__ __forceinline__ f32x16v zero16() {
  f32x16v z;
#pragma unroll
  for (int i = 0; i < 16; ++i) z[i] = 0.f;
  return z;
}

__global__ __launch_bounds__(256, 2) void gemm_gi(
    const float* __restrict__ x, const float* __restrict__ Wih,
    const float* __restrict__ bih, const float* __restrict__ bhh,
    f16* __restrict__ gi) {
  __shared__ u32 bl[16384];  // 128 rows x 128 dwords (f16x2) = 64KB
  const int tid = threadIdx.x;
  const int lane = tid & 63;
  const int wv = tid >> 6;
  const int wr = wv >> 1, wc = wv & 1;
  const int l31 = lane & 31, lh = lane >> 5;
  const int m0 = blockIdx.x << 7;

  u32x4v afr[2][16];
#pragma unroll
  for (int fr = 0; fr < 2; ++fr) {
#pragma unroll
    for (int km = 0; km < 16; ++km) {
      int row = m0 + wr * 64 + fr * 32 + l31;
      int k0 = km * 16 + lh * 8;
      const f32x4v* p = (const f32x4v*)(x + (size_t)row * 256 + k0);
      f32x4v u = p[0], v = p[1];
      u32x4v t;
      t.x = pk2(u.x, u.y); t.y = pk2(u.z, u.w);
      t.z = pk2(v.x, v.y); t.w = pk2(v.z, v.w);
      afr[fr][km] = t;
    }
  }

  for (int nt = 0; nt < 6; ++nt) {
    const int n0 = nt << 7;
    // stage B tile with b128 loads: 32 f32x4 per thread
#pragma unroll
    for (int it = 0; it < 32; ++it) {
      int flat = it * 256 + tid;      // f32x4 index in tile [0, 8192)
      int r = flat >> 6;              // row 0..127
      int q = flat & 63;              // f32x4 within row
      f32x4v f = *(const f32x4v*)(Wih + (size_t)(n0 + r) * 256 + 4 * q);
      u32x2v pw;
      pw.x = pk2(f.x, f.y);
      pw.y = pk2(f.z, f.w);
      int wd = 2 * q;
      *(u32x2v*)&bl[r * 128 + (wd ^ ((r & 15) << 2))] = pw;
    }
    __syncthreads();

    f32x16v acc00 = zero16(), acc01 = zero16(), acc10 = zero16(), acc11 = zero16();
#pragma unroll
    for (int km = 0; km < 16; ++km) {
      int w0 = km * 8 + lh * 4;
      int rc0 = wc * 64 + l31;
      int rc1 = wc * 64 + 32 + l31;
      u32x4v b0 = *(const u32x4v*)&bl[rc0 * 128 + (w0 ^ ((rc0 & 15) << 2))];
      u32x4v b1 = *(const u32x4v*)&bl[rc1 * 128 + (w0 ^ ((rc1 & 15) << 2))];
      h8 a0h = __builtin_bit_cast(h8, afr[0][km]);
      h8 a1h = __builtin_bit_cast(h8, afr[1][km]);
      h8 b0h = __builtin_bit_cast(h8, b0);
      h8 b1h = __builtin_bit_cast(h8, b1);
      acc00 = __builtin_amdgcn_mfma_f32_32x32x16_f16(a0h, b0h, acc00, 0, 0, 0);
      acc10 = __builtin_amdgcn_mfma_f32_32x32x16_f16(a1h, b0h, acc10, 0, 0, 0);
      acc01 = __builtin_amdgcn_mfma_f32_32x32x16_f16(a0h, b1h, acc01, 0, 0, 0);
      acc11 = __builtin_amdgcn_mfma_f32_32x32x16_f16(a1h, b1h, acc11, 0, 0, 0);
    }

#define EPI(ACC, FR, FC)                                                      \
    {                                                                         \
      int gc = n0 + wc * 64 + (FC) * 32 + l31;                                \
      float bias = bih[gc] + (gc < 512 ? bhh[gc] : 0.f);                      \
      _Pragma("unroll")                                                       \
      for (int rg = 0; rg < 16; ++rg) {                                       \
        int gr = m0 + wr * 64 + (FR) * 32 + 4 * lh + (rg & 3) + 8 * (rg >> 2);\
        gi[(size_t)gr * 768 + gc] = (f16)(ACC[rg] + bias);                    \
      }                                                                       \
    }
    EPI(acc00, 0, 0) EPI(acc10, 1, 0) EPI(acc01, 0, 1) EPI(acc11, 1, 1)
#undef EPI
    __syncthreads();
  }
}

// ---------------------------------------------------------------------------
// Phase 2: recurrence via MFMA, W_hh resident in AGPRs.
// 8 blocks x 8 batches, 512 thr (8 waves, 2/SIMD).  Per step:
//   gh(768x16) = W_hh @ H(256x16; cols 8..15 zero) : 48 mfma_16x16x32_f16/wave
//   via the BUILTIN (compiler handles MFMA->VALU hazards), A-operand pinned
//   into AGPRs ("+a" asm pin, 192 AGPR/lane, cannot be rematerialized).
// h in LDS in B-fragment order [ks][g][batch16][e8] (conflict-free b128),
// double-buffered -> 1 barrier/step.  Wave w owns gate-triples (r,z,n) for
// units [32w,32w+32); one row_shr:8 DPP rebalances so all 64 lanes do gates.
// ---------------------------------------------------------------------------
__global__ __launch_bounds__(512, 2) void recur(
    const u32* __restrict__ Wa, const f16* __restrict__ gi,
    const float* __restrict__ states, const float* __restrict__ mask,
    const float* __restrict__ bhh_g, float* __restrict__ out) {
  const int blk = blockIdx.x;
  const int tid = threadIdx.x;
  const int w = tid >> 6, l = tid & 63;
  const int lr = l & 15, g = l >> 4;
  const int c = lr & 7, tj = lr >> 3;
  const int u0 = 32 * w + 16 * tj + 4 * g;   // post-rebalance unit quad base

  __shared__ __align__(16) f16 hb[2][4096];  // [ks][g][batch16][e8]
  __shared__ f16 mlds[8192];                 // [t][batch8]

  // ---- load W fragments, park in AGPRs ----
  u32x4v wa[48];
  {
    const u32x4v* wap = (const u32x4v*)Wa + (size_t)(w * 64 + l) * 48;
#pragma unroll
    for (int i = 0; i < 48; ++i) wa[i] = wap[i];
#pragma unroll
    for (int i = 0; i < 48; ++i) asm volatile("" : "+a"(wa[i]));
  }

  // ---- stage mask as f16 [t][8] ----
  for (int idx = tid; idx < 8192; idx += 512) {
    int b8 = idx >> 10, tt = idx & 1023;
    mlds[tt * 8 + b8] = (f16)mask[(size_t)(blk * 8 + b8) * TT + tt];
  }
  // ---- h0 into both buffers (batch cols 8..15 = 0 forever) ----
  for (int idx = tid; idx < 4096; idx += 512) {
    int unit = idx >> 4, cc = idx & 15;
    float v = 0.f;
    if (cc < 8)
      v = states[(size_t)(blk * 8 + cc) * HH + unit] *
          mask[(size_t)(blk * 8 + cc) * TT];
    int fa = (unit >> 5) * 512 + ((unit >> 3) & 3) * 128 + cc * 8 + (unit & 7);
    hb[0][fa] = (f16)v;
    hb[1][fa] = (f16)v;
  }

  const f16* gip = gi + (size_t)(blk * 8 + c) * TT * GG + u0;
  float* outp = out + (size_t)(blk * 8 + c) * TT * HH + u0;

  float hreg[4];
  {
    float m0 = mask[(size_t)(blk * 8 + c) * TT];
    const f32x4v s4 = *(const f32x4v*)(states + (size_t)(blk * 8 + c) * HH + u0);
#pragma unroll
    for (int r = 0; r < 4; ++r) hreg[r] = s4[r] * m0;
  }
  const f32x4v bn4 = *(const f32x4v*)(bhh_g + 512 + u0);  // b_hh for n-gate only

  const int wbase = w * 512 + ((2 * tj + (g >> 1)) & 3) * 128 + c * 8 + 4 * (g & 1);
  const int rbase = g * 128 + lr * 8;  // + ks*512

  f32x4v nhp = {0.f, 0.f, 0.f, 0.f};
  __syncthreads();

  for (int t = 0; t < TT; ++t) {
    // deferred store of step t-1's nh (drains at NEXT barrier, off crit path)
    if (t > 0) *(f32x4v*)(outp + (size_t)(t - 1) * HH) = nhp;
    // gi for this step (consumed ~400cyc later at gate phase)
    const h4 ldA = *(const h4*)(gip + (size_t)t * GG);
    const h4 ldB = *(const h4*)(gip + (size_t)t * GG + 256);
    const h4 ldC = *(const h4*)(gip + (size_t)t * GG + 512);
    const float mt = (float)mlds[t * 8 + c];

    const u32x4v* bp = (const u32x4v*)&hb[t & 1][rbase];
    f32x4v a0 = {0.f, 0.f, 0.f, 0.f}, a1 = a0, a2 = a0, a3 = a0, a4 = a0, a5 = a0;
    u32x4v bf = bp[0];
#pragma unroll
    for (int ks = 0; ks < 8; ++ks) {
      u32x4v bnx = bp[((ks + 1) & 7) * 64];  // prefetch next K-slice (wraps, dead last)
      h8 bh = __builtin_bit_cast(h8, bf);
      a0 = __builtin_amdgcn_mfma_f32_16x16x32_f16(__builtin_bit_cast(h8, wa[ks]),      bh, a0, 0, 0, 0);
      a1 = __builtin_amdgcn_mfma_f32_16x16x32_f16(__builtin_bit_cast(h8, wa[8 + ks]),  bh, a1, 0, 0, 0);
      a2 = __builtin_amdgcn_mfma_f32_16x16x32_f16(__builtin_bit_cast(h8, wa[16 + ks]), bh, a2, 0, 0, 0);
      a3 = __builtin_amdgcn_mfma_f32_16x16x32_f16(__builtin_bit_cast(h8, wa[24 + ks]), bh, a3, 0, 0, 0);
      a4 = __builtin_amdgcn_mfma_f32_16x16x32_f16(__builtin_bit_cast(h8, wa[32 + ks]), bh, a4, 0, 0, 0);
      a5 = __builtin_amdgcn_mfma_f32_16x16x32_f16(__builtin_bit_cast(h8, wa[40 + ks]), bh, a5, 0, 0, 0);
      bf = bnx;
    }

    // rebalance: lanes lr>=8 take triple tj=1 (batch lr-8) from lane l-8
    const bool hi = (lr >= 8);
    f32x4v vr, vz, vn;
#pragma unroll
    for (int r = 0; r < 4; ++r) {
      float d0 = dpp_shr8(a1[r]);
      float d1 = dpp_shr8(a3[r]);
      float d2 = dpp_shr8(a5[r]);
      vr[r] = hi ? d0 : a0[r];
      vz[r] = hi ? d1 : a2[r];
      vn[r] = hi ? d2 : a4[r];
    }

#pragma unroll
    for (int r = 0; r < 4; ++r) {
      float rr = sigf((float)ldA[r] + vr[r]);
      float zz = sigf((float)ldB[r] + vz[r]);
      float nn = tanhf2((float)ldC[r] + rr * (vn[r] + bn4[r]));
      float nh = zz * (hreg[r] - nn) + nn;     // (1-z)n + z h
      hreg[r] = hreg[r] + mt * (nh - hreg[r]); // mask blend
      nhp[r] = nh;
    }
    u32x2v hp;
    hp.x = pk2(hreg[0], hreg[1]);
    hp.y = pk2(hreg[2], hreg[3]);
    *(u32x2v*)&hb[(t + 1) & 1][wbase] = hp;
    __syncthreads();
  }

  *(f32x4v*)(outp + (size_t)(TT - 1) * HH) = nhp;
  f32x4v hf;
#pragma unroll
  for (int r = 0; r < 4; ++r) hf[r] = hreg[r];
  *(f32x4v*)(out + (size_t)BB * TT * HH + (size_t)(blk * 8 + c) * HH + u0) = hf;
}

extern "C" void kernel_launch(void* const* d_in, const int* in_sizes, int n_in,
                              void* d_out, int out_size, void* d_ws, size_t ws_size,
                              hipStream_t stream) {
  const float* x      = (const float*)d_in[0];
  const float* states = (const float*)d_in[1];
  const float* mask   = (const float*)d_in[2];
  const float* W_ih   = (const float*)d_in[3];
  const float* W_hh   = (const float*)d_in[4];
  const float* b_ih   = (const float*)d_in[5];
  const float* b_hh   = (const float*)d_in[6];
  float* out = (float*)d_out;

  char* ws = (char*)d_ws;
  f16* gi = (f16*)ws;
  u32* Wa = (u32*)(ws + GI_BYTES);

  prepack_wa<<<dim3(384), dim3(256), 0, stream>>>(W_hh, Wa);
  gemm_gi<<<dim3(512), dim3(256), 0, stream>>>(x, W_ih, b_ih, b_hh, gi);
  recur<<<dim3(8), dim3(512), 0, stream>>>(Wa, gi, states, mask, b_hh, out);
}